// Round 1
// baseline (330.842 us; speedup 1.0000x reference)
//
#include <hip/hip_runtime.h>

// TwoLayerSAGE on MI355X (gfx950).
// B=8, N=2048, IN_C=128, HID_C=256, OUT_C=32.
// Strategy: all heavy math via v_mfma_f32_16x16x32_bf16 (fp32 accumulate).
//   mask = (A!=0) is exact in bf16; deg computed in-GEMM via ones-fragment MFMA.
// ws layout (20.6 MB): W1cT | W2cT | deg_inv | agg1 | h | agg2

#define B_   8
#define N_   2048
#define INC  128
#define HID  256
#define OUTC 32

typedef __bf16 bf16;
typedef __attribute__((ext_vector_type(8))) __bf16 bf16x8;
typedef __attribute__((ext_vector_type(4))) float f32x4;
typedef __attribute__((ext_vector_type(4))) unsigned int u32x4;
typedef __attribute__((ext_vector_type(2))) unsigned int u32x2;

__device__ __forceinline__ unsigned short f2bf(float f) {
  unsigned int u = __float_as_uint(f);
  u += 0x7FFFu + ((u >> 16) & 1u);   // round-to-nearest-even
  return (unsigned short)(u >> 16);
}

__device__ __forceinline__ f32x4 mfma16(bf16x8 a, bf16x8 b, f32x4 c) {
  return __builtin_amdgcn_mfma_f32_16x16x32_bf16(a, b, c, 0, 0, 0);
}

__device__ __forceinline__ bf16x8 ones_frag() {
  union { unsigned short u[8]; bf16x8 v; } o;
#pragma unroll
  for (int i = 0; i < 8; i++) o.u[i] = 0x3F80;  // 1.0 bf16
  return o.v;
}

// ---------------------------------------------------------------------------
// Pack weights: W1cT[e][k] (k<128 -> W1_l[k][e], else W1_r[k-128][e]), bf16.
//               W2cT[c][k] (k<256 -> W2_l[k][c], else W2_r[k-256][c]), bf16.
__global__ __launch_bounds__(256) void k_pack_w(
    const float* __restrict__ W1l, const float* __restrict__ W1r,
    const float* __restrict__ W2l, const float* __restrict__ W2r,
    unsigned short* __restrict__ W1cT, unsigned short* __restrict__ W2cT) {
  int idx = blockIdx.x * 256 + threadIdx.x;  // 0..65535
  {
    int e = idx >> 8, k = idx & 255;
    float v = (k < 128) ? W1l[k * 256 + e] : W1r[(k - 128) * 256 + e];
    W1cT[idx] = f2bf(v);
  }
  if (idx < 32 * 512) {
    int c = idx >> 9, k = idx & 511;
    float v = (k < 256) ? W2l[k * 32 + c] : W2r[(k - 256) * 32 + c];
    W2cT[idx] = f2bf(v);
  }
}

// ---------------------------------------------------------------------------
// Layer-1 aggregation: agg1[b][j][d] = deg_inv[b][j] * sum_i mask[b][i][j]*x[b][i][d]
// Also computes deg_inv via ones-fragment MFMA.
// Block: 512 thr (8 waves: wj=w&3 -> 16 j, wd=w>>2 -> 64 d). Grid (32, 8).
__global__ __launch_bounds__(512) void k_agg1(
    const int* __restrict__ A, const float* __restrict__ x,
    unsigned short* __restrict__ agg1, float* __restrict__ deg_inv) {
#define KP 40  // padded LDS row (elems); row stride 80B = 5*16B (b128-aligned)
  __shared__ __align__(16) unsigned short mts[64 * KP];   // maskT [j][i]
  __shared__ __align__(16) unsigned short xts[INC * KP];  // xT    [d][i]
  const int b = blockIdx.y;
  const int j0 = blockIdx.x * 64;
  const int t = threadIdx.x;
  const int w = t >> 6, l = t & 63;
  const int wj = w & 3, wd = w >> 2;
  const int lr = l & 15, lq = l >> 4;

  const f32x4 zero = {0.f, 0.f, 0.f, 0.f};
  f32x4 acc[4] = {zero, zero, zero, zero};
  f32x4 dacc = zero;
  const bf16x8 onesf = ones_frag();

  const int sj = t & 63;           // mask stage: column j
  const int si4 = (t >> 6) << 2;   // mask stage: rows i4..i4+3
  const int* Ab = A + (size_t)b * N_ * N_ + j0 + sj;
  const int sd = t & 127;          // x stage: column d
  const int si8 = (t >> 7) << 3;   // x stage: rows i8..i8+7
  const float* xb = x + (size_t)b * N_ * INC + sd;

  for (int k0 = 0; k0 < N_; k0 += 32) {
    __syncthreads();
    {  // stage mask tile [32 i][64 j] -> mts[j][i], bf16 0/1
      const int* ap = Ab + (size_t)(k0 + si4) * N_;
      int a0 = ap[0], a1 = ap[N_], a2 = ap[2 * N_], a3 = ap[3 * N_];
      u32x2 p;
      p.x = (a0 ? 0x3F80u : 0u) | ((a1 ? 0x3F80u : 0u) << 16);
      p.y = (a2 ? 0x3F80u : 0u) | ((a3 ? 0x3F80u : 0u) << 16);
      *reinterpret_cast<u32x2*>(&mts[sj * KP + si4]) = p;
    }
    {  // stage x tile [32 i][128 d] -> xts[d][i], fp32 -> bf16
      const float* xp = xb + (size_t)(k0 + si8) * INC;
      u32x4 p;
#pragma unroll
      for (int q = 0; q < 4; q++) {
        unsigned int lo = f2bf(xp[(2 * q) * INC]);
        unsigned int hi = f2bf(xp[(2 * q + 1) * INC]);
        p[q] = lo | (hi << 16);
      }
      *reinterpret_cast<u32x4*>(&xts[sd * KP + si8]) = p;
    }
    __syncthreads();
    bf16x8 af = *reinterpret_cast<const bf16x8*>(&mts[(wj * 16 + lr) * KP + lq * 8]);
    dacc = mfma16(af, onesf, dacc);  // deg: sum_i mask[i][j]
#pragma unroll
    for (int ds = 0; ds < 4; ds++) {
      bf16x8 bfr = *reinterpret_cast<const bf16x8*>(&xts[(wd * 64 + ds * 16 + lr) * KP + lq * 8]);
      acc[ds] = mfma16(af, bfr, acc[ds]);
    }
  }

  float dinv[4];
#pragma unroll
  for (int r = 0; r < 4; r++) dinv[r] = 1.0f / fmaxf(dacc[r], 1.0f);
  if (wd == 0 && lr == 0) {
#pragma unroll
    for (int r = 0; r < 4; r++)
      deg_inv[b * N_ + j0 + wj * 16 + lq * 4 + r] = dinv[r];
  }
  unsigned short* ag = agg1 + ((size_t)b * N_ + j0) * INC;
#pragma unroll
  for (int ds = 0; ds < 4; ds++)
#pragma unroll
    for (int r = 0; r < 4; r++) {
      int j = wj * 16 + lq * 4 + r;   // C/D: row=(l>>4)*4+reg
      int d = wd * 64 + ds * 16 + lr; // C/D: col=lane&15
      ag[(size_t)j * INC + d] = f2bf(acc[ds][r] * dinv[r]);
    }
#undef KP
}

// ---------------------------------------------------------------------------
// Layer-1 dense: h = relu([agg1 | x] @ [W1_l; W1_r] + b1), K=256 staged once.
// Block: 512 thr (wj=w&3 -> 16 j, we=w>>2 -> 128 e). Grid (32, 8).
__global__ __launch_bounds__(512) void k_dense1(
    const unsigned short* __restrict__ agg1, const float* __restrict__ x,
    const unsigned short* __restrict__ W1cT, const float* __restrict__ b1,
    unsigned short* __restrict__ h) {
  __shared__ __align__(16) unsigned short acat[64 * 264];  // [j][k], pad 8
  const int b = blockIdx.y;
  const int j0 = blockIdx.x * 64;
  const int t = threadIdx.x;
  const int w = t >> 6, l = t & 63;
  const int wj = w & 3, we = w >> 2;
  const int lr = l & 15, lq = l >> 4;

  {  // stage Acat rows: cols 0..127 from agg1 (bf16), 128..255 from x (fp32->bf16)
    const int sj = t >> 3, seg = t & 7;
    u32x4* dst = reinterpret_cast<u32x4*>(&acat[sj * 264 + seg * 32]);
    if (seg < 4) {
      const u32x4* src = reinterpret_cast<const u32x4*>(
          agg1 + ((size_t)(b * N_ + j0 + sj)) * INC + seg * 32);
#pragma unroll
      for (int q = 0; q < 4; q++) dst[q] = src[q];
    } else {
      const float* src = x + ((size_t)(b * N_ + j0 + sj)) * INC + (seg - 4) * 32;
#pragma unroll
      for (int q = 0; q < 4; q++) {
        u32x4 p;
#pragma unroll
        for (int e = 0; e < 4; e++) {
          unsigned int lo = f2bf(src[q * 8 + 2 * e]);
          unsigned int hi = f2bf(src[q * 8 + 2 * e + 1]);
          p[e] = lo | (hi << 16);
        }
        dst[q] = p;
      }
    }
  }
  __syncthreads();

  const f32x4 zero = {0.f, 0.f, 0.f, 0.f};
  f32x4 acc[8] = {zero, zero, zero, zero, zero, zero, zero, zero};
#pragma unroll
  for (int ks = 0; ks < 8; ks++) {
    bf16x8 af = *reinterpret_cast<const bf16x8*>(&acat[(wj * 16 + lr) * 264 + ks * 32 + lq * 8]);
#pragma unroll
    for (int es = 0; es < 8; es++) {
      bf16x8 bfr = *reinterpret_cast<const bf16x8*>(
          W1cT + (we * 128 + es * 16 + lr) * 256 + ks * 32 + lq * 8);
      acc[es] = mfma16(af, bfr, acc[es]);
    }
  }

  unsigned short* hB = h + ((size_t)b * N_ + j0) * HID;
#pragma unroll
  for (int es = 0; es < 8; es++) {
    int e = we * 128 + es * 16 + lr;
    float bias = b1[e];
#pragma unroll
    for (int r = 0; r < 4; r++) {
      int j = wj * 16 + lq * 4 + r;
      float v = fmaxf(acc[es][r] + bias, 0.0f);
      hB[(size_t)j * HID + e] = f2bf(v);
    }
  }
}

// ---------------------------------------------------------------------------
// Layer-2 aggregation: agg2[b][j][e] = deg_inv[b][j] * sum_i mask[b][i][j]*h[b][i][e]
// Block: 512 thr (wj=w&3 -> 16 j, we=w>>2 -> 128 e). Grid (32, 8).
__global__ __launch_bounds__(512) void k_agg2(
    const int* __restrict__ A, const unsigned short* __restrict__ h,
    const float* __restrict__ deg_inv, unsigned short* __restrict__ agg2) {
#define KP 40
  __shared__ __align__(16) unsigned short mts[64 * KP];   // maskT [j][i]
  __shared__ __align__(16) unsigned short hts[HID * KP];  // hT    [e][i]
  const int b = blockIdx.y;
  const int j0 = blockIdx.x * 64;
  const int t = threadIdx.x;
  const int w = t >> 6, l = t & 63;
  const int wj = w & 3, we = w >> 2;
  const int lr = l & 15, lq = l >> 4;

  const f32x4 zero = {0.f, 0.f, 0.f, 0.f};
  f32x4 acc[8] = {zero, zero, zero, zero, zero, zero, zero, zero};

  const int sj = t & 63;
  const int si4 = (t >> 6) << 2;
  const int* Ab = A + (size_t)b * N_ * N_ + j0 + sj;
  const int se2 = (t & 127) * 2;   // h stage: two e-rows se2, se2+1
  const int si8 = (t >> 7) << 3;   // h stage: rows i8..i8+7
  const unsigned short* hb = h + (size_t)b * N_ * HID + se2;

  for (int k0 = 0; k0 < N_; k0 += 32) {
    __syncthreads();
    {
      const int* ap = Ab + (size_t)(k0 + si4) * N_;
      int a0 = ap[0], a1 = ap[N_], a2 = ap[2 * N_], a3 = ap[3 * N_];
      u32x2 p;
      p.x = (a0 ? 0x3F80u : 0u) | ((a1 ? 0x3F80u : 0u) << 16);
      p.y = (a2 ? 0x3F80u : 0u) | ((a3 ? 0x3F80u : 0u) << 16);
      *reinterpret_cast<u32x2*>(&mts[sj * KP + si4]) = p;
    }
    {  // stage h tile [32 i][256 e] -> hts[e][i] (transpose via ushort2 loads)
      const unsigned short* hp = hb + (size_t)(k0 + si8) * HID;
      unsigned int vv[8];
#pragma unroll
      for (int q = 0; q < 8; q++)
        vv[q] = *reinterpret_cast<const unsigned int*>(hp + (size_t)q * HID);
      u32x4 p0, p1;
#pragma unroll
      for (int q4 = 0; q4 < 4; q4++) {
        p0[q4] = (vv[2 * q4] & 0xFFFFu) | ((vv[2 * q4 + 1] & 0xFFFFu) << 16);
        p1[q4] = (vv[2 * q4] >> 16) | ((vv[2 * q4 + 1] >> 16) << 16);
      }
      *reinterpret_cast<u32x4*>(&hts[se2 * KP + si8]) = p0;
      *reinterpret_cast<u32x4*>(&hts[(se2 + 1) * KP + si8]) = p1;
    }
    __syncthreads();
    bf16x8 af = *reinterpret_cast<const bf16x8*>(&mts[(wj * 16 + lr) * KP + lq * 8]);
#pragma unroll
    for (int es = 0; es < 8; es++) {
      bf16x8 bfr = *reinterpret_cast<const bf16x8*>(&hts[(we * 128 + es * 16 + lr) * KP + lq * 8]);
      acc[es] = mfma16(af, bfr, acc[es]);
    }
  }

  float dinv[4];
#pragma unroll
  for (int r = 0; r < 4; r++)
    dinv[r] = deg_inv[b * N_ + j0 + wj * 16 + lq * 4 + r];
  unsigned short* ag = agg2 + ((size_t)b * N_ + j0) * HID;
#pragma unroll
  for (int es = 0; es < 8; es++) {
    int e = we * 128 + es * 16 + lr;
#pragma unroll
    for (int r = 0; r < 4; r++) {
      int j = wj * 16 + lq * 4 + r;
      ag[(size_t)j * HID + e] = f2bf(acc[es][r] * dinv[r]);
    }
  }
#undef KP
}

// ---------------------------------------------------------------------------
// Layer-2 dense + log_softmax: out = [agg2 | h] @ [W2_l; W2_r] + b2  (K=512)
// d_out[0:524288] = log_softmax(out), d_out[524288:1048576] = out.
// Block: 256 thr (4 waves, wave wj -> 16 j, full 32 classes). Grid (32, 8).
__global__ __launch_bounds__(256) void k_out(
    const unsigned short* __restrict__ agg2, const unsigned short* __restrict__ h,
    const unsigned short* __restrict__ W2cT, const float* __restrict__ b2,
    float* __restrict__ out) {
  __shared__ __align__(16) unsigned short acat[64 * 136];  // [j][128k chunk], pad 8
  const int b = blockIdx.y;
  const int j0 = blockIdx.x * 64;
  const int t = threadIdx.x;
  const int w = t >> 6, l = t & 63;
  const int lr = l & 15, lq = l >> 4;
  const int wj = w;

  const f32x4 zero = {0.f, 0.f, 0.f, 0.f};
  f32x4 acc[2] = {zero, zero};

  const int sj = t >> 2, seg = t & 3;
  const unsigned short* a2B = agg2 + (size_t)b * N_ * HID;
  const unsigned short* hB = h + (size_t)b * N_ * HID;

  for (int kc = 0; kc < 4; kc++) {
    __syncthreads();
    {
      int kcol = kc * 128 + seg * 32;
      const unsigned short* src = (kcol < 256)
          ? (a2B + (size_t)(j0 + sj) * HID + kcol)
          : (hB + (size_t)(j0 + sj) * HID + (kcol - 256));
      u32x4* dst = reinterpret_cast<u32x4*>(&acat[sj * 136 + seg * 32]);
      const u32x4* s4 = reinterpret_cast<const u32x4*>(src);
#pragma unroll
      for (int q = 0; q < 4; q++) dst[q] = s4[q];
    }
    __syncthreads();
#pragma unroll
    for (int ks = 0; ks < 4; ks++) {
      bf16x8 af = *reinterpret_cast<const bf16x8*>(&acat[(wj * 16 + lr) * 136 + ks * 32 + lq * 8]);
#pragma unroll
      for (int cs = 0; cs < 2; cs++) {
        bf16x8 bfr = *reinterpret_cast<const bf16x8*>(
            W2cT + (cs * 16 + lr) * 512 + kc * 128 + ks * 32 + lq * 8);
        acc[cs] = mfma16(af, bfr, acc[cs]);
      }
    }
  }

  float v[2][4];
#pragma unroll
  for (int cs = 0; cs < 2; cs++) {
    float bias = b2[cs * 16 + lr];
#pragma unroll
    for (int r = 0; r < 4; r++) v[cs][r] = acc[cs][r] + bias;
  }
#pragma unroll
  for (int r = 0; r < 4; r++) {
    // row j's 32 classes live in lanes (same lq) x 2 regs; reduce over low 4 lane bits
    float m = fmaxf(v[0][r], v[1][r]);
    for (int d = 1; d < 16; d <<= 1) m = fmaxf(m, __shfl_xor(m, d, 64));
    float s = __expf(v[0][r] - m) + __expf(v[1][r] - m);
    for (int d = 1; d < 16; d <<= 1) s += __shfl_xor(s, d, 64);
    float ls = m + __logf(s);
    int j = j0 + wj * 16 + lq * 4 + r;
    size_t base = ((size_t)b * N_ + j) * OUTC;
#pragma unroll
    for (int cs = 0; cs < 2; cs++) {
      out[base + cs * 16 + lr] = v[cs][r] - ls;                 // log_softmax
      out[(size_t)B_ * N_ * OUTC + base + cs * 16 + lr] = v[cs][r];  // raw out
    }
  }
}

// ---------------------------------------------------------------------------
extern "C" void kernel_launch(void* const* d_in, const int* in_sizes, int n_in,
                              void* d_out, int out_size, void* d_ws, size_t ws_size,
                              hipStream_t stream) {
  (void)in_sizes; (void)n_in; (void)out_size; (void)ws_size;
  const float* x   = (const float*)d_in[0];
  const int*   A   = (const int*)d_in[1];
  const float* W1l = (const float*)d_in[2];
  const float* W1r = (const float*)d_in[3];
  const float* b1  = (const float*)d_in[4];
  const float* W2l = (const float*)d_in[5];
  const float* W2r = (const float*)d_in[6];
  const float* b2  = (const float*)d_in[7];
  float* out = (float*)d_out;

  char* ws = (char*)d_ws;
  unsigned short* W1cT    = (unsigned short*)(ws + 0);         // 256*256*2 = 131072
  unsigned short* W2cT    = (unsigned short*)(ws + 131072);    // 32*512*2  = 32768
  float*          deg_inv = (float*)(ws + 163840);             // 8*2048*4  = 65536
  unsigned short* agg1    = (unsigned short*)(ws + 229376);    // 8*2048*128*2 = 4 MB
  unsigned short* h       = (unsigned short*)(ws + 4423680);   // 8*2048*256*2 = 8 MB
  unsigned short* agg2    = (unsigned short*)(ws + 12812288);  // 8 MB; end 21200896

  k_pack_w<<<dim3(256), dim3(256), 0, stream>>>(W1l, W1r, W2l, W2r, W1cT, W2cT);
  k_agg1  <<<dim3(32, 8), dim3(512), 0, stream>>>(A, x, agg1, deg_inv);
  k_dense1<<<dim3(32, 8), dim3(512), 0, stream>>>(agg1, x, W1cT, b1, h);
  k_agg2  <<<dim3(32, 8), dim3(512), 0, stream>>>(A, h, deg_inv, agg2);
  k_out   <<<dim3(32, 8), dim3(256), 0, stream>>>(agg2, h, W2cT, b2, out);
}